// Round 15
// baseline (300.587 us; speedup 1.0000x reference)
//
#include <hip/hip_runtime.h>
#include <hip/hip_bf16.h>

#define N_ATOMS 32768
#define N_EDGESC 262144
#define ATOM_F 256
#define EDGE_F 128
#define OUT_F 512
#define N_GAUSS 50
#define IN_F 690
#define NCHUNK 11

#define BM 128
#define BN 256
#define NTHREADS 512

using f32x4  = __attribute__((ext_vector_type(4))) float;
using short8 = __attribute__((ext_vector_type(8))) short;

__device__ __forceinline__ unsigned short f2bf(float f) {
  unsigned int u = __builtin_bit_cast(unsigned int, f);
  u += 0x7fffu + ((u >> 16) & 1u);   // round-to-nearest-even
  return (unsigned short)(u >> 16);
}

// ---- h (32768x256 f32) -> hb (bf16, row-major) ----
__global__ void prep_h_kernel(const float* __restrict__ h, unsigned short* __restrict__ hb) {
  size_t i = (size_t)(blockIdx.x * blockDim.x + threadIdx.x) * 8;
  if (i >= (size_t)N_ATOMS * ATOM_F) return;
  float4 a = *(const float4*)(h + i);
  float4 b = *(const float4*)(h + i + 4);
  uint4 o;
  o.x = (unsigned)f2bf(a.x) | ((unsigned)f2bf(a.y) << 16);
  o.y = (unsigned)f2bf(a.z) | ((unsigned)f2bf(a.w) << 16);
  o.z = (unsigned)f2bf(b.x) | ((unsigned)f2bf(b.y) << 16);
  o.w = (unsigned)f2bf(b.z) | ((unsigned)f2bf(b.w) << 16);
  *(uint4*)(hb + i) = o;
}

// ---- W -> Wp bf16 fragments; also detect int64-vs-int32 edge_index ----
// Fragment (kc, ks, nt): 64 lanes x 16B contiguous (1 KB).
// lane l holds B[n = nt*16 + (l&15)][k = kc*64 + ks*32 + (l>>4)*8 + j], j=0..7
__global__ void prep_w_kernel(const float* __restrict__ W, unsigned short* __restrict__ Wp,
                              const unsigned int* __restrict__ ei, int* __restrict__ flag) {
  if (blockIdx.x == 0 && threadIdx.x == 0) {
    int ok = 1;
    for (int i = 0; i < 64; ++i) {
      unsigned int lo = ei[2 * i], hi = ei[2 * i + 1];
      if (hi != 0u || lo >= (unsigned)N_ATOMS) { ok = 0; break; }
    }
    *flag = ok;  // 1 => int64 layout
  }
  int g = blockIdx.x * blockDim.x + threadIdx.x;
  if (g >= NCHUNK * 2 * 32 * 64) return;
  int l  = g & 63;
  int nt = (g >> 6) & 31;
  int ks = (g >> 11) & 1;
  int kc = g >> 12;
  int n  = nt * 16 + (l & 15);
  int k0 = kc * 64 + ks * 32 + ((l >> 4) << 3);
  unsigned int u[4];
#pragma unroll
  for (int p = 0; p < 4; ++p) {
    int ka = k0 + 2 * p, kb = k0 + 2 * p + 1;
    float va = (ka < IN_F) ? W[n * IN_F + ka] : 0.0f;
    float vb = (kb < IN_F) ? W[n * IN_F + kb] : 0.0f;
    u[p] = (unsigned)f2bf(va) | ((unsigned)f2bf(vb) << 16);
  }
  *(uint4*)(Wp + (size_t)g * 8) = make_uint4(u[0], u[1], u[2], u[3]);
}

// ---- fused gather + gaussian + GEMM ----
// BM=128 x BN=256; 8 waves (2M x 4N, wave tile 64x64); 2 blocks/CU.
// K-order [8,9,10,0..7]; reg-path chunks staged in prologue.
// PAIRED SEGMENTS (round-13): 2 chunks per sync window, stages into buffers
// freed by the previous barrier; 6 barriers total.
// Non-temporal out stores + m loads (keep Wp/hb hot in L2).
__global__ __launch_bounds__(NTHREADS, 4) void gemm_kernel(
    const unsigned short* __restrict__ hb, const float* __restrict__ m,
    const float* __restrict__ magft, const void* __restrict__ ei,
    const int* __restrict__ flagp, const unsigned short* __restrict__ Wp,
    float* __restrict__ out)
{
  __shared__ __align__(16) unsigned short As[4][BM * 64];  // 4 x 16 KB
  __shared__ int sIdx[BM], tIdx[BM];
  __shared__ float dLDS[BM];

  const int tid = threadIdx.x;
  const int bid = blockIdx.x;
  // decode so the two n-halves of an edge-block are 8 dispatches apart (same XCD)
  const int e  = (bid & 7) | ((bid >> 4) << 3);
  const int nh = (bid >> 3) & 1;
  const int eb = e * BM;

  const int use64 = *flagp;
  if (tid < BM) {
    int ed = eb + tid;
    int s, tg;
    if (use64) {
      const long long* p = (const long long*)ei;
      s  = (int)p[ed];
      tg = (int)p[N_EDGESC + ed];
    } else {
      const int* p = (const int*)ei;
      s  = p[ed];
      tg = p[N_EDGESC + ed];
    }
    sIdx[tid] = s;
    tIdx[tid] = tg;
    float ax = magft[3 * s],  ay = magft[3 * s + 1],  az = magft[3 * s + 2];
    float bx = magft[3 * tg], by = magft[3 * tg + 1], bz = magft[3 * tg + 2];
    dLDS[tid] = ax * bx + ay * by + az * bz;
  }
  __syncthreads();

  const int lane = tid & 63;
  const int wid  = tid >> 6;     // 0..7
  const int wr   = wid >> 2;     // M half
  const int wc   = wid & 3;      // N quarter

  // glds geometry: wave wid covers rows [wid*16, wid*16+16), 2 instrs x 1KB.
  const int r0 = wid * 16 + (lane >> 3);       // row for j=0 (j=1 is r0+8)
  const int hs0 = sIdx[r0], hs1 = sIdx[r0 + 8];
  const int ht0 = tIdx[r0], ht1 = tIdx[r0 + 8];
  // pre-swizzled source byte offset within the 128B row-slice (row&7 == lane>>3)
  const int srcsw = (((lane & 7) ^ (lane >> 3)) << 4);

  const int ar = tid >> 2;       // reg-path staging row 0..127
  const int aq = tid & 3;        // 16-col quarter

  // h-chunk stage via global_load_lds (kchunk 0..7 only)
  auto stage_h = [&](int kchunk, int buf) {
    int a0 = (kchunk < 4) ? hs0 : ht0;
    int a1 = (kchunk < 4) ? hs1 : ht1;
    const unsigned short* s0 = hb + (size_t)a0 * ATOM_F + (kchunk & 3) * 64;
    const unsigned short* s1 = hb + (size_t)a1 * ATOM_F + (kchunk & 3) * 64;
    char* d0 = (char*)&As[buf][0] + wid * 2048;
    __builtin_amdgcn_global_load_lds(
        (const __attribute__((address_space(1))) void*)((const char*)s0 + srcsw),
        (__attribute__((address_space(3))) void*)d0, 16, 0, 0);
    __builtin_amdgcn_global_load_lds(
        (const __attribute__((address_space(1))) void*)((const char*)s1 + srcsw),
        (__attribute__((address_space(3))) void*)(d0 + 1024), 16, 0, 0);
  };

  // m / gaussian reg-path stage (kchunk 8..10; prologue only)
  auto stage_reg = [&](int kchunk, int buf) {
    char* base = (char*)&As[buf][0] + ar * 128;
    const int sw = (ar & 7) << 4;
    if (kchunk < 10) {
      const f32x4* p = (const f32x4*)(m + (size_t)(eb + ar) * EDGE_F + (kchunk & 1) * 64 + aq * 16);
#pragma unroll
      for (int hh = 0; hh < 2; ++hh) {
        f32x4 v0 = __builtin_nontemporal_load(p + 2 * hh);
        f32x4 v1 = __builtin_nontemporal_load(p + 2 * hh + 1);
        uint4 o;
        o.x = (unsigned)f2bf(v0[0]) | ((unsigned)f2bf(v0[1]) << 16);
        o.y = (unsigned)f2bf(v0[2]) | ((unsigned)f2bf(v0[3]) << 16);
        o.z = (unsigned)f2bf(v1[0]) | ((unsigned)f2bf(v1[1]) << 16);
        o.w = (unsigned)f2bf(v1[2]) | ((unsigned)f2bf(v1[3]) << 16);
        *(uint4*)(base + ((aq * 32 + hh * 16) ^ sw)) = o;
      }
    } else {
      float d = dLDS[ar];
      const float step  = 3.0f / 49.0f;
      const float coeff = -0.5f / (step * step);
#pragma unroll
      for (int hh = 0; hh < 2; ++hh) {
        unsigned int u[4];
#pragma unroll
        for (int p2 = 0; p2 < 4; ++p2) {
          int c0 = aq * 16 + hh * 8 + 2 * p2, c1 = c0 + 1;
          float o0 = -1.5f + step * (float)c0;
          float o1 = -1.5f + step * (float)c1;
          float w0 = (c0 < N_GAUSS) ? __expf(coeff * (d - o0) * (d - o0)) : 0.0f;
          float w1 = (c1 < N_GAUSS) ? __expf(coeff * (d - o1) * (d - o1)) : 0.0f;
          u[p2] = (unsigned)f2bf(w0) | ((unsigned)f2bf(w1) << 16);
        }
        *(uint4*)(base + ((aq * 32 + hh * 16) ^ sw)) = make_uint4(u[0], u[1], u[2], u[3]);
      }
    }
  };

  f32x4 acc[4][4];
#pragma unroll
  for (int i = 0; i < 4; ++i)
#pragma unroll
    for (int j = 0; j < 4; ++j) acc[i][j] = (f32x4){0.f, 0.f, 0.f, 0.f};

  const short8* Wp8 = (const short8*)Wp;

  auto compute = [&](int kc, int buf) {
    const char* abase = (const char*)&As[buf][0];
#pragma unroll
    for (int ks = 0; ks < 2; ++ks) {
      short8 b[4];
#pragma unroll
      for (int ni = 0; ni < 4; ++ni) {
        int nt = nh * 16 + wc * 4 + ni;
        b[ni] = Wp8[(size_t)(((kc * 2 + ks) * 32 + nt) << 6) + lane];
      }
      short8 a[4];
#pragma unroll
      for (int mi = 0; mi < 4; ++mi) {
        int row = wr * 64 + mi * 16 + (lane & 15);
        int colb = (ks * 64 + ((lane >> 4) << 4)) ^ ((row & 7) << 4);
        a[mi] = *(const short8*)(abase + row * 128 + colb);
      }
      __builtin_amdgcn_s_setprio(1);
#pragma unroll
      for (int mi = 0; mi < 4; ++mi)
#pragma unroll
        for (int ni = 0; ni < 4; ++ni)
          acc[mi][ni] = __builtin_amdgcn_mfma_f32_16x16x32_bf16(a[mi], b[ni], acc[mi][ni], 0, 0, 0);
      __builtin_amdgcn_s_setprio(0);
    }
  };

  // ---- prologue: reg-path chunks; order 8,10,9 so gauss VALU covers m8 load ----
  stage_reg(8, 0);
  stage_reg(10, 2);
  stage_reg(9, 1);
  __syncthreads();

  // ---- paired segments: stage next pair into bufs freed by previous barrier ----
  stage_h(0, 3);
  compute(8, 0);
  compute(9, 1);
  __syncthreads();
  stage_h(1, 0);
  stage_h(2, 1);
  compute(10, 2);
  compute(0, 3);
  __syncthreads();
  stage_h(3, 2);
  stage_h(4, 3);
  compute(1, 0);
  compute(2, 1);
  __syncthreads();
  stage_h(5, 0);
  stage_h(6, 1);
  compute(3, 2);
  compute(4, 3);
  __syncthreads();
  stage_h(7, 2);
  compute(5, 0);
  compute(6, 1);
  __syncthreads();
  compute(7, 2);

  // ---- epilogue: C/D layout col=lane&15, row=(lane>>4)*4+j; NT stores ----
#pragma unroll
  for (int mi = 0; mi < 4; ++mi) {
    int row0 = eb + wr * 64 + mi * 16 + ((lane >> 4) << 2);
#pragma unroll
    for (int ni = 0; ni < 4; ++ni) {
      int col = nh * 256 + wc * 64 + ni * 16 + (lane & 15);
#pragma unroll
      for (int j = 0; j < 4; ++j) {
        __builtin_nontemporal_store(acc[mi][ni][j], &out[(size_t)(row0 + j) * OUT_F + col]);
      }
    }
  }
}

extern "C" void kernel_launch(void* const* d_in, const int* in_sizes, int n_in,
                              void* d_out, int out_size, void* d_ws, size_t ws_size,
                              hipStream_t stream) {
  const float* h     = (const float*)d_in[0];
  const float* m     = (const float*)d_in[1];
  const float* magft = (const float*)d_in[2];
  const void*  ei    = d_in[3];
  const float* W     = (const float*)d_in[4];
  float* out = (float*)d_out;

  char* ws = (char*)d_ws;
  int* flag = (int*)ws;
  unsigned short* Wp = (unsigned short*)(ws + 256);            // 704 KB
  unsigned short* hb = (unsigned short*)(ws + 256 + 720896);   // 16 MB bf16 h

  prep_w_kernel<<<(NCHUNK * 2 * 32 * 64 + 255) / 256, 256, 0, stream>>>(
      W, Wp, (const unsigned int*)ei, flag);
  prep_h_kernel<<<(N_ATOMS * ATOM_F / 8 + 255) / 256, 256, 0, stream>>>(h, hb);

  gemm_kernel<<<dim3(2 * N_EDGESC / BM), NTHREADS, 0, stream>>>(hb, m, magft, ei, flag, Wp, out);
}

// Round 16
// 285.686 us; speedup vs baseline: 1.0522x; 1.0522x over previous
//
#include <hip/hip_runtime.h>
#include <hip/hip_bf16.h>

#define N_ATOMS 32768
#define N_EDGESC 262144
#define ATOM_F 256
#define EDGE_F 128
#define OUT_F 512
#define N_GAUSS 50
#define IN_F 690
#define NCHUNK 11

#define BM 256
#define BN 256
#define NTHREADS 1024

using f32x4  = __attribute__((ext_vector_type(4))) float;
using short8 = __attribute__((ext_vector_type(8))) short;

__device__ __forceinline__ unsigned short f2bf(float f) {
  unsigned int u = __builtin_bit_cast(unsigned int, f);
  u += 0x7fffu + ((u >> 16) & 1u);   // round-to-nearest-even
  return (unsigned short)(u >> 16);
}

// ---- h (32768x256 f32) -> hb (bf16, row-major) ----
__global__ void prep_h_kernel(const float* __restrict__ h, unsigned short* __restrict__ hb) {
  size_t i = (size_t)(blockIdx.x * blockDim.x + threadIdx.x) * 8;
  if (i >= (size_t)N_ATOMS * ATOM_F) return;
  float4 a = *(const float4*)(h + i);
  float4 b = *(const float4*)(h + i + 4);
  uint4 o;
  o.x = (unsigned)f2bf(a.x) | ((unsigned)f2bf(a.y) << 16);
  o.y = (unsigned)f2bf(a.z) | ((unsigned)f2bf(a.w) << 16);
  o.z = (unsigned)f2bf(b.x) | ((unsigned)f2bf(b.y) << 16);
  o.w = (unsigned)f2bf(b.z) | ((unsigned)f2bf(b.w) << 16);
  *(uint4*)(hb + i) = o;
}

// ---- W -> Wp bf16 fragments; also detect int64-vs-int32 edge_index ----
// Fragment (kc, ks, nt): 64 lanes x 16B contiguous (1 KB).
// lane l holds B[n = nt*16 + (l&15)][k = kc*64 + ks*32 + (l>>4)*8 + j], j=0..7
__global__ void prep_w_kernel(const float* __restrict__ W, unsigned short* __restrict__ Wp,
                              const unsigned int* __restrict__ ei, int* __restrict__ flag) {
  if (blockIdx.x == 0 && threadIdx.x == 0) {
    int ok = 1;
    for (int i = 0; i < 64; ++i) {
      unsigned int lo = ei[2 * i], hi = ei[2 * i + 1];
      if (hi != 0u || lo >= (unsigned)N_ATOMS) { ok = 0; break; }
    }
    *flag = ok;  // 1 => int64 layout
  }
  int g = blockIdx.x * blockDim.x + threadIdx.x;
  if (g >= NCHUNK * 2 * 32 * 64) return;
  int l  = g & 63;
  int nt = (g >> 6) & 31;
  int ks = (g >> 11) & 1;
  int kc = g >> 12;
  int n  = nt * 16 + (l & 15);
  int k0 = kc * 64 + ks * 32 + ((l >> 4) << 3);
  unsigned int u[4];
#pragma unroll
  for (int p = 0; p < 4; ++p) {
    int ka = k0 + 2 * p, kb = k0 + 2 * p + 1;
    float va = (ka < IN_F) ? W[n * IN_F + ka] : 0.0f;
    float vb = (kb < IN_F) ? W[n * IN_F + kb] : 0.0f;
    u[p] = (unsigned)f2bf(va) | ((unsigned)f2bf(vb) << 16);
  }
  *(uint4*)(Wp + (size_t)g * 8) = make_uint4(u[0], u[1], u[2], u[3]);
}

// ---- fused gather + gaussian + GEMM ----
// BM=256 x BN=256; 16 waves (4M x 4N, wave tile 64x64); 1 block/CU.
// Halves L2 B-fragment traffic and L3 gather traffic vs BM=128.
// K-order [8,9,10,0..7]; reg-path chunks staged in prologue.
// PAIRED SEGMENTS: 2 chunks per sync window, staged into buffers freed by
// the previous barrier; 6 barriers total.
__global__ __launch_bounds__(NTHREADS, 4) void gemm_kernel(
    const unsigned short* __restrict__ hb, const float* __restrict__ m,
    const float* __restrict__ magft, const void* __restrict__ ei,
    const int* __restrict__ flagp, const unsigned short* __restrict__ Wp,
    float* __restrict__ out)
{
  __shared__ __align__(16) unsigned short As[4][BM * 64];  // 4 x 32 KB
  __shared__ int sIdx[BM], tIdx[BM];
  __shared__ float dLDS[BM];

  const int tid = threadIdx.x;
  const int bid = blockIdx.x;
  // decode so the two n-halves of an edge-block are 8 dispatches apart (same XCD)
  const int e  = (bid & 7) | ((bid >> 4) << 3);   // 0..1023
  const int nh = (bid >> 3) & 1;
  const int eb = e * BM;

  const int use64 = *flagp;
  if (tid < BM) {
    int ed = eb + tid;
    int s, tg;
    if (use64) {
      const long long* p = (const long long*)ei;
      s  = (int)p[ed];
      tg = (int)p[N_EDGESC + ed];
    } else {
      const int* p = (const int*)ei;
      s  = p[ed];
      tg = p[N_EDGESC + ed];
    }
    sIdx[tid] = s;
    tIdx[tid] = tg;
    float ax = magft[3 * s],  ay = magft[3 * s + 1],  az = magft[3 * s + 2];
    float bx = magft[3 * tg], by = magft[3 * tg + 1], bz = magft[3 * tg + 2];
    dLDS[tid] = ax * bx + ay * by + az * bz;
  }
  __syncthreads();

  const int lane = tid & 63;
  const int wid  = tid >> 6;     // 0..15
  const int wr   = wid >> 2;     // M quarter (0..3)
  const int wc   = wid & 3;      // N quarter (0..3)

  // glds geometry: wave wid covers rows [wid*16, wid*16+16), 2 instrs x 1KB.
  const int r0 = wid * 16 + (lane >> 3);       // row for j=0 (j=1 is r0+8)
  const int hs0 = sIdx[r0], hs1 = sIdx[r0 + 8];
  const int ht0 = tIdx[r0], ht1 = tIdx[r0 + 8];
  // pre-swizzled source byte offset within the 128B row-slice (row&7 == lane>>3)
  const int srcsw = (((lane & 7) ^ (lane >> 3)) << 4);

  const int ar = tid >> 2;       // reg-path staging row 0..255
  const int aq = tid & 3;        // 16-col quarter

  // h-chunk stage via global_load_lds (kchunk 0..7 only)
  auto stage_h = [&](int kchunk, int buf) {
    int a0 = (kchunk < 4) ? hs0 : ht0;
    int a1 = (kchunk < 4) ? hs1 : ht1;
    const unsigned short* s0 = hb + (size_t)a0 * ATOM_F + (kchunk & 3) * 64;
    const unsigned short* s1 = hb + (size_t)a1 * ATOM_F + (kchunk & 3) * 64;
    char* d0 = (char*)&As[buf][0] + wid * 2048;
    __builtin_amdgcn_global_load_lds(
        (const __attribute__((address_space(1))) void*)((const char*)s0 + srcsw),
        (__attribute__((address_space(3))) void*)d0, 16, 0, 0);
    __builtin_amdgcn_global_load_lds(
        (const __attribute__((address_space(1))) void*)((const char*)s1 + srcsw),
        (__attribute__((address_space(3))) void*)(d0 + 1024), 16, 0, 0);
  };

  // m / gaussian reg-path stage (kchunk 8..10; prologue only)
  auto stage_reg = [&](int kchunk, int buf) {
    char* base = (char*)&As[buf][0] + ar * 128;
    const int sw = (ar & 7) << 4;
    if (kchunk < 10) {
      const float* p = m + (size_t)(eb + ar) * EDGE_F + (kchunk & 1) * 64 + aq * 16;
#pragma unroll
      for (int hh = 0; hh < 2; ++hh) {
        float4 v0 = ((const float4*)p)[2 * hh];
        float4 v1 = ((const float4*)p)[2 * hh + 1];
        uint4 o;
        o.x = (unsigned)f2bf(v0.x) | ((unsigned)f2bf(v0.y) << 16);
        o.y = (unsigned)f2bf(v0.z) | ((unsigned)f2bf(v0.w) << 16);
        o.z = (unsigned)f2bf(v1.x) | ((unsigned)f2bf(v1.y) << 16);
        o.w = (unsigned)f2bf(v1.z) | ((unsigned)f2bf(v1.w) << 16);
        *(uint4*)(base + ((aq * 32 + hh * 16) ^ sw)) = o;
      }
    } else {
      float d = dLDS[ar];
      const float step  = 3.0f / 49.0f;
      const float coeff = -0.5f / (step * step);
#pragma unroll
      for (int hh = 0; hh < 2; ++hh) {
        unsigned int u[4];
#pragma unroll
        for (int p2 = 0; p2 < 4; ++p2) {
          int c0 = aq * 16 + hh * 8 + 2 * p2, c1 = c0 + 1;
          float o0 = -1.5f + step * (float)c0;
          float o1 = -1.5f + step * (float)c1;
          float w0 = (c0 < N_GAUSS) ? __expf(coeff * (d - o0) * (d - o0)) : 0.0f;
          float w1 = (c1 < N_GAUSS) ? __expf(coeff * (d - o1) * (d - o1)) : 0.0f;
          u[p2] = (unsigned)f2bf(w0) | ((unsigned)f2bf(w1) << 16);
        }
        *(uint4*)(base + ((aq * 32 + hh * 16) ^ sw)) = make_uint4(u[0], u[1], u[2], u[3]);
      }
    }
  };

  f32x4 acc[4][4];
#pragma unroll
  for (int i = 0; i < 4; ++i)
#pragma unroll
    for (int j = 0; j < 4; ++j) acc[i][j] = (f32x4){0.f, 0.f, 0.f, 0.f};

  const short8* Wp8 = (const short8*)Wp;

  auto compute = [&](int kc, int buf) {
    const char* abase = (const char*)&As[buf][0];
#pragma unroll
    for (int ks = 0; ks < 2; ++ks) {
      short8 b[4];
#pragma unroll
      for (int ni = 0; ni < 4; ++ni) {
        int nt = nh * 16 + wc * 4 + ni;
        b[ni] = Wp8[(size_t)(((kc * 2 + ks) * 32 + nt) << 6) + lane];
      }
      short8 a[4];
#pragma unroll
      for (int mi = 0; mi < 4; ++mi) {
        int row = wr * 64 + mi * 16 + (lane & 15);
        int colb = (ks * 64 + ((lane >> 4) << 4)) ^ ((row & 7) << 4);
        a[mi] = *(const short8*)(abase + row * 128 + colb);
      }
      __builtin_amdgcn_s_setprio(1);
#pragma unroll
      for (int mi = 0; mi < 4; ++mi)
#pragma unroll
        for (int ni = 0; ni < 4; ++ni)
          acc[mi][ni] = __builtin_amdgcn_mfma_f32_16x16x32_bf16(a[mi], b[ni], acc[mi][ni], 0, 0, 0);
      __builtin_amdgcn_s_setprio(0);
    }
  };

  // ---- prologue: reg-path chunks; order 8,10,9 so gauss VALU covers m8 load ----
  stage_reg(8, 0);
  stage_reg(10, 2);
  stage_reg(9, 1);
  __syncthreads();

  // ---- paired segments: stage next pair into bufs freed by previous barrier ----
  stage_h(0, 3);
  compute(8, 0);
  compute(9, 1);
  __syncthreads();
  stage_h(1, 0);
  stage_h(2, 1);
  compute(10, 2);
  compute(0, 3);
  __syncthreads();
  stage_h(3, 2);
  stage_h(4, 3);
  compute(1, 0);
  compute(2, 1);
  __syncthreads();
  stage_h(5, 0);
  stage_h(6, 1);
  compute(3, 2);
  compute(4, 3);
  __syncthreads();
  stage_h(7, 2);
  compute(5, 0);
  compute(6, 1);
  __syncthreads();
  compute(7, 2);

  // ---- epilogue: C/D layout col=lane&15, row=(lane>>4)*4+j ----
#pragma unroll
  for (int mi = 0; mi < 4; ++mi) {
    int row0 = eb + wr * 64 + mi * 16 + ((lane >> 4) << 2);
#pragma unroll
    for (int ni = 0; ni < 4; ++ni) {
      int col = nh * 256 + wc * 64 + ni * 16 + (lane & 15);
#pragma unroll
      for (int j = 0; j < 4; ++j) {
        out[(size_t)(row0 + j) * OUT_F + col] = acc[mi][ni][j];
      }
    }
  }
}

extern "C" void kernel_launch(void* const* d_in, const int* in_sizes, int n_in,
                              void* d_out, int out_size, void* d_ws, size_t ws_size,
                              hipStream_t stream) {
  const float* h     = (const float*)d_in[0];
  const float* m     = (const float*)d_in[1];
  const float* magft = (const float*)d_in[2];
  const void*  ei    = d_in[3];
  const float* W     = (const float*)d_in[4];
  float* out = (float*)d_out;

  char* ws = (char*)d_ws;
  int* flag = (int*)ws;
  unsigned short* Wp = (unsigned short*)(ws + 256);            // 704 KB
  unsigned short* hb = (unsigned short*)(ws + 256 + 720896);   // 16 MB bf16 h

  prep_w_kernel<<<(NCHUNK * 2 * 32 * 64 + 255) / 256, 256, 0, stream>>>(
      W, Wp, (const unsigned int*)ei, flag);
  prep_h_kernel<<<(N_ATOMS * ATOM_F / 8 + 255) / 256, 256, 0, stream>>>(h, hb);

  gemm_kernel<<<dim3(2 * N_EDGESC / BM), NTHREADS, 0, stream>>>(hb, m, magft, ei, flag, Wp, out);
}

// Round 17
// 271.333 us; speedup vs baseline: 1.1078x; 1.0529x over previous
//
#include <hip/hip_runtime.h>
#include <hip/hip_bf16.h>

#define N_ATOMS 32768
#define N_EDGESC 262144
#define ATOM_F 256
#define EDGE_F 128
#define OUT_F 512
#define N_GAUSS 50
#define IN_F 690
#define NCHUNK 11

#define BM 128
#define BN 256
#define NTHREADS 512

using f32x4  = __attribute__((ext_vector_type(4))) float;
using short8 = __attribute__((ext_vector_type(8))) short;

__device__ __forceinline__ unsigned short f2bf(float f) {
  unsigned int u = __builtin_bit_cast(unsigned int, f);
  u += 0x7fffu + ((u >> 16) & 1u);   // round-to-nearest-even
  return (unsigned short)(u >> 16);
}

// ---- h (32768x256 f32) -> hb (bf16, row-major) ----
__global__ void prep_h_kernel(const float* __restrict__ h, unsigned short* __restrict__ hb) {
  size_t i = (size_t)(blockIdx.x * blockDim.x + threadIdx.x) * 8;
  if (i >= (size_t)N_ATOMS * ATOM_F) return;
  float4 a = *(const float4*)(h + i);
  float4 b = *(const float4*)(h + i + 4);
  uint4 o;
  o.x = (unsigned)f2bf(a.x) | ((unsigned)f2bf(a.y) << 16);
  o.y = (unsigned)f2bf(a.z) | ((unsigned)f2bf(a.w) << 16);
  o.z = (unsigned)f2bf(b.x) | ((unsigned)f2bf(b.y) << 16);
  o.w = (unsigned)f2bf(b.z) | ((unsigned)f2bf(b.w) << 16);
  *(uint4*)(hb + i) = o;
}

// ---- W -> Wp bf16 fragments; also detect int64-vs-int32 edge_index ----
// Fragment (kc, ks, nt): 64 lanes x 16B contiguous (1 KB).
// lane l holds B[n = nt*16 + (l&15)][k = kc*64 + ks*32 + (l>>4)*8 + j], j=0..7
__global__ void prep_w_kernel(const float* __restrict__ W, unsigned short* __restrict__ Wp,
                              const unsigned int* __restrict__ ei, int* __restrict__ flag) {
  if (blockIdx.x == 0 && threadIdx.x == 0) {
    int ok = 1;
    for (int i = 0; i < 64; ++i) {
      unsigned int lo = ei[2 * i], hi = ei[2 * i + 1];
      if (hi != 0u || lo >= (unsigned)N_ATOMS) { ok = 0; break; }
    }
    *flag = ok;  // 1 => int64 layout
  }
  int g = blockIdx.x * blockDim.x + threadIdx.x;
  if (g >= NCHUNK * 2 * 32 * 64) return;
  int l  = g & 63;
  int nt = (g >> 6) & 31;
  int ks = (g >> 11) & 1;
  int kc = g >> 12;
  int n  = nt * 16 + (l & 15);
  int k0 = kc * 64 + ks * 32 + ((l >> 4) << 3);
  unsigned int u[4];
#pragma unroll
  for (int p = 0; p < 4; ++p) {
    int ka = k0 + 2 * p, kb = k0 + 2 * p + 1;
    float va = (ka < IN_F) ? W[n * IN_F + ka] : 0.0f;
    float vb = (kb < IN_F) ? W[n * IN_F + kb] : 0.0f;
    u[p] = (unsigned)f2bf(va) | ((unsigned)f2bf(vb) << 16);
  }
  *(uint4*)(Wp + (size_t)g * 8) = make_uint4(u[0], u[1], u[2], u[3]);
}

// ---- fused gather + gaussian + GEMM (r13 structure, best known) ----
// BM=128 x BN=256; 8 waves (2M x 4N, wave tile 64x64); 2 blocks/CU.
// K-order [8,9,10,0..7]; reg-path chunks + h0 prefetch staged in prologue
// (prologue barrier is lgkmcnt-only so h0's glds ride across it).
// PAIRED SEGMENTS: 2 chunks per sync window, staged into buffers freed by
// the previous barrier; 6 barriers total.
__global__ __launch_bounds__(NTHREADS, 4) void gemm_kernel(
    const unsigned short* __restrict__ hb, const float* __restrict__ m,
    const float* __restrict__ magft, const void* __restrict__ ei,
    const int* __restrict__ flagp, const unsigned short* __restrict__ Wp,
    float* __restrict__ out)
{
  __shared__ __align__(16) unsigned short As[4][BM * 64];  // 4 x 16 KB
  __shared__ int sIdx[BM], tIdx[BM];
  __shared__ float dLDS[BM];

  const int tid = threadIdx.x;
  const int bid = blockIdx.x;
  // decode so the two n-halves of an edge-block are 8 dispatches apart (same XCD)
  const int e  = (bid & 7) | ((bid >> 4) << 3);
  const int nh = (bid >> 3) & 1;
  const int eb = e * BM;

  const int use64 = *flagp;
  if (tid < BM) {
    int ed = eb + tid;
    int s, tg;
    if (use64) {
      const long long* p = (const long long*)ei;
      s  = (int)p[ed];
      tg = (int)p[N_EDGESC + ed];
    } else {
      const int* p = (const int*)ei;
      s  = p[ed];
      tg = p[N_EDGESC + ed];
    }
    sIdx[tid] = s;
    tIdx[tid] = tg;
    float ax = magft[3 * s],  ay = magft[3 * s + 1],  az = magft[3 * s + 2];
    float bx = magft[3 * tg], by = magft[3 * tg + 1], bz = magft[3 * tg + 2];
    dLDS[tid] = ax * bx + ay * by + az * bz;
  }
  __syncthreads();

  const int lane = tid & 63;
  const int wid  = tid >> 6;     // 0..7
  const int wr   = wid >> 2;     // M half
  const int wc   = wid & 3;      // N quarter

  // glds geometry: wave wid covers rows [wid*16, wid*16+16), 2 instrs x 1KB.
  const int r0 = wid * 16 + (lane >> 3);       // row for j=0 (j=1 is r0+8)
  const int hs0 = sIdx[r0], hs1 = sIdx[r0 + 8];
  const int ht0 = tIdx[r0], ht1 = tIdx[r0 + 8];
  // pre-swizzled source byte offset within the 128B row-slice (row&7 == lane>>3)
  const int srcsw = (((lane & 7) ^ (lane >> 3)) << 4);

  const int ar = tid >> 2;       // reg-path staging row 0..127
  const int aq = tid & 3;        // 16-col quarter

  // h-chunk stage via global_load_lds (kchunk 0..7 only)
  auto stage_h = [&](int kchunk, int buf) {
    int a0 = (kchunk < 4) ? hs0 : ht0;
    int a1 = (kchunk < 4) ? hs1 : ht1;
    const unsigned short* s0 = hb + (size_t)a0 * ATOM_F + (kchunk & 3) * 64;
    const unsigned short* s1 = hb + (size_t)a1 * ATOM_F + (kchunk & 3) * 64;
    char* d0 = (char*)&As[buf][0] + wid * 2048;
    __builtin_amdgcn_global_load_lds(
        (const __attribute__((address_space(1))) void*)((const char*)s0 + srcsw),
        (__attribute__((address_space(3))) void*)d0, 16, 0, 0);
    __builtin_amdgcn_global_load_lds(
        (const __attribute__((address_space(1))) void*)((const char*)s1 + srcsw),
        (__attribute__((address_space(3))) void*)(d0 + 1024), 16, 0, 0);
  };

  // m / gaussian reg-path stage (kchunk 8..10; prologue only)
  auto stage_reg = [&](int kchunk, int buf) {
    char* base = (char*)&As[buf][0] + ar * 128;
    const int sw = (ar & 7) << 4;
    if (kchunk < 10) {
      const float* p = m + (size_t)(eb + ar) * EDGE_F + (kchunk & 1) * 64 + aq * 16;
#pragma unroll
      for (int hh = 0; hh < 2; ++hh) {
        float4 v0 = ((const float4*)p)[2 * hh];
        float4 v1 = ((const float4*)p)[2 * hh + 1];
        uint4 o;
        o.x = (unsigned)f2bf(v0.x) | ((unsigned)f2bf(v0.y) << 16);
        o.y = (unsigned)f2bf(v0.z) | ((unsigned)f2bf(v0.w) << 16);
        o.z = (unsigned)f2bf(v1.x) | ((unsigned)f2bf(v1.y) << 16);
        o.w = (unsigned)f2bf(v1.z) | ((unsigned)f2bf(v1.w) << 16);
        *(uint4*)(base + ((aq * 32 + hh * 16) ^ sw)) = o;
      }
    } else {
      float d = dLDS[ar];
      const float step  = 3.0f / 49.0f;
      const float coeff = -0.5f / (step * step);
#pragma unroll
      for (int hh = 0; hh < 2; ++hh) {
        unsigned int u[4];
#pragma unroll
        for (int p2 = 0; p2 < 4; ++p2) {
          int c0 = aq * 16 + hh * 8 + 2 * p2, c1 = c0 + 1;
          float o0 = -1.5f + step * (float)c0;
          float o1 = -1.5f + step * (float)c1;
          float w0 = (c0 < N_GAUSS) ? __expf(coeff * (d - o0) * (d - o0)) : 0.0f;
          float w1 = (c1 < N_GAUSS) ? __expf(coeff * (d - o1) * (d - o1)) : 0.0f;
          u[p2] = (unsigned)f2bf(w0) | ((unsigned)f2bf(w1) << 16);
        }
        *(uint4*)(base + ((aq * 32 + hh * 16) ^ sw)) = make_uint4(u[0], u[1], u[2], u[3]);
      }
    }
  };

  f32x4 acc[4][4];
#pragma unroll
  for (int i = 0; i < 4; ++i)
#pragma unroll
    for (int j = 0; j < 4; ++j) acc[i][j] = (f32x4){0.f, 0.f, 0.f, 0.f};

  const short8* Wp8 = (const short8*)Wp;

  auto compute = [&](int kc, int buf) {
    const char* abase = (const char*)&As[buf][0];
#pragma unroll
    for (int ks = 0; ks < 2; ++ks) {
      short8 b[4];
#pragma unroll
      for (int ni = 0; ni < 4; ++ni) {
        int nt = nh * 16 + wc * 4 + ni;
        b[ni] = Wp8[(size_t)(((kc * 2 + ks) * 32 + nt) << 6) + lane];
      }
      short8 a[4];
#pragma unroll
      for (int mi = 0; mi < 4; ++mi) {
        int row = wr * 64 + mi * 16 + (lane & 15);
        int colb = (ks * 64 + ((lane >> 4) << 4)) ^ ((row & 7) << 4);
        a[mi] = *(const short8*)(abase + row * 128 + colb);
      }
      __builtin_amdgcn_s_setprio(1);
#pragma unroll
      for (int mi = 0; mi < 4; ++mi)
#pragma unroll
        for (int ni = 0; ni < 4; ++ni)
          acc[mi][ni] = __builtin_amdgcn_mfma_f32_16x16x32_bf16(a[mi], b[ni], acc[mi][ni], 0, 0, 0);
      __builtin_amdgcn_s_setprio(0);
    }
  };

  // ---- prologue: reg-path chunks (8,10,9: gauss VALU covers m8 latency),
  //      then h0 prefetch; barrier orders only LDS writes (lgkmcnt) so the
  //      h0 glds stay in flight into seg0.
  stage_reg(8, 0);
  stage_reg(10, 2);
  stage_reg(9, 1);
  stage_h(0, 3);
  asm volatile("s_waitcnt lgkmcnt(0)" ::: "memory");
  __builtin_amdgcn_sched_barrier(0);
  __builtin_amdgcn_s_barrier();

  // ---- paired segments: stage next pair into bufs freed by previous barrier ----
  // seg0: compute c8,c9 (bufs 0,1); h0 (-> buf3) still in flight, drained here
  compute(8, 0);
  compute(9, 1);
  __syncthreads();
  // seg1: compute c10,c0 (bufs 2,3); stage h1,h2 -> bufs 0,1
  stage_h(1, 0);
  stage_h(2, 1);
  compute(10, 2);
  compute(0, 3);
  __syncthreads();
  // seg2: compute c1,c2 (bufs 0,1); stage h3,h4 -> bufs 2,3
  stage_h(3, 2);
  stage_h(4, 3);
  compute(1, 0);
  compute(2, 1);
  __syncthreads();
  // seg3: compute c3,c4 (bufs 2,3); stage h5,h6 -> bufs 0,1
  stage_h(5, 0);
  stage_h(6, 1);
  compute(3, 2);
  compute(4, 3);
  __syncthreads();
  // seg4: compute c5,c6 (bufs 0,1); stage h7 -> buf 2
  stage_h(7, 2);
  compute(5, 0);
  compute(6, 1);
  __syncthreads();
  // seg5: compute c7 (buf 2); no barrier
  compute(7, 2);

  // ---- epilogue: C/D layout col=lane&15, row=(lane>>4)*4+j ----
#pragma unroll
  for (int mi = 0; mi < 4; ++mi) {
    int row0 = eb + wr * 64 + mi * 16 + ((lane >> 4) << 2);
#pragma unroll
    for (int ni = 0; ni < 4; ++ni) {
      int col = nh * 256 + wc * 64 + ni * 16 + (lane & 15);
#pragma unroll
      for (int j = 0; j < 4; ++j) {
        out[(size_t)(row0 + j) * OUT_F + col] = acc[mi][ni][j];
      }
    }
  }
}

extern "C" void kernel_launch(void* const* d_in, const int* in_sizes, int n_in,
                              void* d_out, int out_size, void* d_ws, size_t ws_size,
                              hipStream_t stream) {
  const float* h     = (const float*)d_in[0];
  const float* m     = (const float*)d_in[1];
  const float* magft = (const float*)d_in[2];
  const void*  ei    = d_in[3];
  const float* W     = (const float*)d_in[4];
  float* out = (float*)d_out;

  char* ws = (char*)d_ws;
  int* flag = (int*)ws;
  unsigned short* Wp = (unsigned short*)(ws + 256);            // 704 KB
  unsigned short* hb = (unsigned short*)(ws + 256 + 720896);   // 16 MB bf16 h

  prep_w_kernel<<<(NCHUNK * 2 * 32 * 64 + 255) / 256, 256, 0, stream>>>(
      W, Wp, (const unsigned int*)ei, flag);
  prep_h_kernel<<<(N_ATOMS * ATOM_F / 8 + 255) / 256, 256, 0, stream>>>(h, hb);

  gemm_kernel<<<dim3(2 * N_EDGESC / BM), NTHREADS, 0, stream>>>(hb, m, magft, ei, flag, Wp, out);
}